// Round 4
// baseline (859.186 us; speedup 1.0000x reference)
//
#include <hip/hip_runtime.h>
#include <hip/hip_bf16.h>

// RT-DETR multi-scale deformable attention, MI355X (gfx950).
// Round 8: k_vproj reads Wv_bf16 from L2 (no Bs in LDS) -> LDS only holds the
// 64-row Cs transpose buffer (33.8KB) -> up to 4 blocks/CU (32 waves).
// Non-persistent 512-thr blocks, 1 barrier each, full-row coalesced stores
// (R3 lesson: scattered 8B stores amplify WRITE 1.7x and FETCH 3.7x).

#define BS 8
#define LQ 300
#define LEN_V 34000
#define ED 256
#define NH 8
#define NL 4
#define NP 4

typedef short short8 __attribute__((ext_vector_type(8)));
typedef short sv4 __attribute__((ext_vector_type(4)));
typedef float f32x4 __attribute__((ext_vector_type(4)));

__device__ __forceinline__ short8 cvt8_reg(float4 a, float4 b) {
  union { short8 v; __hip_bfloat16 h[8]; } u;
  u.h[0] = __float2bfloat16(a.x); u.h[1] = __float2bfloat16(a.y);
  u.h[2] = __float2bfloat16(a.z); u.h[3] = __float2bfloat16(a.w);
  u.h[4] = __float2bfloat16(b.x); u.h[5] = __float2bfloat16(b.y);
  u.h[6] = __float2bfloat16(b.z); u.h[7] = __float2bfloat16(b.w);
  return u.v;
}

__device__ __forceinline__ void cvt8_store(__hip_bfloat16* dst, float4 a, float4 b) {
  *(short8*)dst = cvt8_reg(a, b);
}

// ---------------- Value projection: C[272000 x 256] = A @ Wv^T + bv (bf16 out)
// Grid 4250 x 512 thr (8 waves). Block tile 64 rows x 256 cols; wave tile
// 32 rows x 64 cols (acc[2][4]). B-fragments read per-step from global
// Wv_bf16 (128KB, L2-resident). A streams global->reg, 1-deep prefetch,
// cvt in-reg. K-loop barrier-free. Epilogue: acc -> Cs[64][264] (disjoint
// per wave), ONE barrier, then 4 passes of full-row 512B-coherent short8
// stores. LDS 33.8KB + <=64 VGPR -> target 4 blocks/CU (32 waves).
__global__ __launch_bounds__(512, 8) void k_vproj(
    const float* __restrict__ A, const __hip_bfloat16* __restrict__ Wb,
    const float* __restrict__ bias, __hip_bfloat16* __restrict__ C) {
  __shared__ __align__(16) __hip_bfloat16 Cs[64][264];  // 33,792 B

  const int t = threadIdx.x;
  const int wave = t >> 6;
  const int lane = t & 63;
  const int wr = wave >> 2;        // row-half 0..1 (32 rows each)
  const int wc = wave & 3;         // col-quad 0..3 (64 cols each)
  const int fr = lane & 15;
  const int fk = (lane >> 4) * 8;  // k sub-range within a 32-k step
  const int rq = (lane >> 4) * 4;  // acc row quad

  const size_t row0 = (size_t)blockIdx.x * 64;
  const float* gA = A + (row0 + wr * 32 + fr) * ED + fk;
  const __hip_bfloat16* gB = Wb + (size_t)(wc * 64 + fr) * ED + fk;

  float bias_v[4];
#pragma unroll
  for (int ni = 0; ni < 4; ++ni) bias_v[ni] = bias[wc * 64 + ni * 16 + fr];

  f32x4 acc[2][4];
#pragma unroll
  for (int i = 0; i < 2; ++i)
#pragma unroll
    for (int j = 0; j < 4; ++j) acc[i][j] = (f32x4){0.f, 0.f, 0.f, 0.f};

  float4 c0[2], c1[2];
#pragma unroll
  for (int mi = 0; mi < 2; ++mi) {
    c0[mi] = *(const float4*)(gA + mi * 16 * ED);
    c1[mi] = *(const float4*)(gA + mi * 16 * ED + 4);
  }

#pragma unroll
  for (int s = 0; s < 8; ++s) {
    const int kk = s * 32;
    float4 p0[2], p1[2];
    if (s < 7) {
#pragma unroll
      for (int mi = 0; mi < 2; ++mi) {
        p0[mi] = *(const float4*)(gA + mi * 16 * ED + kk + 32);
        p1[mi] = *(const float4*)(gA + mi * 16 * ED + kk + 36);
      }
    }
    short8 af[2], bf[4];
#pragma unroll
    for (int mi = 0; mi < 2; ++mi) af[mi] = cvt8_reg(c0[mi], c1[mi]);
#pragma unroll
    for (int ni = 0; ni < 4; ++ni)
      bf[ni] = *(const short8*)(gB + (size_t)ni * 16 * ED + kk);
#pragma unroll
    for (int mi = 0; mi < 2; ++mi)
#pragma unroll
      for (int ni = 0; ni < 4; ++ni)
        acc[mi][ni] = __builtin_amdgcn_mfma_f32_16x16x32_bf16(
            af[mi], bf[ni], acc[mi][ni], 0, 0, 0);
    if (s < 7) {
#pragma unroll
      for (int mi = 0; mi < 2; ++mi) { c0[mi] = p0[mi]; c1[mi] = p1[mi]; }
    }
  }

  // ---- epilogue: transpose through Cs (disjoint per wave), one barrier ----
#pragma unroll
  for (int mi = 0; mi < 2; ++mi)
#pragma unroll
    for (int ni = 0; ni < 4; ++ni) {
      const int col = wc * 64 + ni * 16 + fr;
      const int rb = wr * 32 + mi * 16 + rq;
#pragma unroll
      for (int r = 0; r < 4; ++r)
        Cs[rb + r][col] = __float2bfloat16(acc[mi][ni][r] + bias_v[ni]);
    }
  __syncthreads();
  // full-row coherent stores: each pass writes 16 complete 512B rows
#pragma unroll
  for (int p = 0; p < 4; ++p) {
    const int rr = p * 16 + (t >> 5);
    const int cb = (t & 31) * 8;
    *(short8*)(C + (row0 + rr) * ED + cb) = *(const short8*)&Cs[rr][cb];
  }
}

// ---------------- Small MFMA GEMM: C[M x ldc] = A[M x 256] @ B[N x 256]^T + bias
// Block 256 thr (4 waves), tile 64x64, BK=64 (4 K-steps), K=256.
#define LDT64 72  // 64 + 8 pad

template <typename OutT>
__global__ __launch_bounds__(256) void k_gemm64(
    const float* __restrict__ A, const float* __restrict__ B,
    const float* __restrict__ bias, OutT* __restrict__ C, int M, int ldc) {
  __shared__ __align__(16) __hip_bfloat16 As[64][LDT64];
  __shared__ __align__(16) __hip_bfloat16 Bs[64][LDT64];

  const int t = threadIdx.x;
  const size_t row0 = (size_t)blockIdx.x * 64;
  const int n0 = blockIdx.y * 64;

  const int sr = t >> 2;          // staging row 0..63
  const int sc = (t & 3) * 16;    // staging f32 col offset

  const int wave = t >> 6;
  const int lane = t & 63;
  const int mw = (wave & 1) * 32;
  const int nw = (wave >> 1) * 32;
  const int fr = lane & 15;
  const int fk = (lane >> 4) * 8;

  f32x4 acc[2][2];
#pragma unroll
  for (int i = 0; i < 2; ++i)
#pragma unroll
    for (int j = 0; j < 2; ++j) acc[i][j] = (f32x4){0.f, 0.f, 0.f, 0.f};

  const size_t rA = min(row0 + sr, (size_t)(M - 1));
  const float* gA = A + rA * ED + sc;
  const float* gB = B + (size_t)(n0 + sr) * ED + sc;

  for (int kk = 0; kk < ED; kk += 64) {
    float4 a0 = ((const float4*)(gA + kk))[0];
    float4 a1 = ((const float4*)(gA + kk))[1];
    float4 a2 = ((const float4*)(gA + kk))[2];
    float4 a3 = ((const float4*)(gA + kk))[3];
    float4 b0 = ((const float4*)(gB + kk))[0];
    float4 b1 = ((const float4*)(gB + kk))[1];
    float4 b2 = ((const float4*)(gB + kk))[2];
    float4 b3 = ((const float4*)(gB + kk))[3];
    __syncthreads();
    cvt8_store(&As[sr][sc], a0, a1);
    cvt8_store(&As[sr][sc + 8], a2, a3);
    cvt8_store(&Bs[sr][sc], b0, b1);
    cvt8_store(&Bs[sr][sc + 8], b2, b3);
    __syncthreads();

#pragma unroll
    for (int ks = 0; ks < 2; ++ks) {
      short8 afrag[2], bfrag[2];
#pragma unroll
      for (int mi = 0; mi < 2; ++mi)
        afrag[mi] = *(const short8*)&As[mw + mi * 16 + fr][ks * 32 + fk];
#pragma unroll
      for (int ni = 0; ni < 2; ++ni)
        bfrag[ni] = *(const short8*)&Bs[nw + ni * 16 + fr][ks * 32 + fk];
#pragma unroll
      for (int mi = 0; mi < 2; ++mi)
#pragma unroll
        for (int ni = 0; ni < 2; ++ni)
          acc[mi][ni] = __builtin_amdgcn_mfma_f32_16x16x32_bf16(
              afrag[mi], bfrag[ni], acc[mi][ni], 0, 0, 0);
    }
  }

  const int rq = (lane >> 4) * 4;
#pragma unroll
  for (int ni = 0; ni < 2; ++ni) {
    const int col = n0 + nw + ni * 16 + fr;
    const float bias_v = bias[col];
#pragma unroll
    for (int mi = 0; mi < 2; ++mi) {
      const size_t rbase = row0 + mw + mi * 16 + rq;
#pragma unroll
      for (int r = 0; r < 4; ++r) {
        const size_t row = rbase + r;
        if (row < (size_t)M)
          C[row * (size_t)ldc + col] = acc[mi][ni][r] + bias_v;
      }
    }
  }
}

// ---- Concat Woff+Wattn -> Wcat(384x256), and convert Wv -> bf16 (L2-resident B)
__global__ __launch_bounds__(256) void k_concat(
    const float* __restrict__ Woff, const float* __restrict__ boff,
    const float* __restrict__ Wattn, const float* __restrict__ battn,
    float* __restrict__ Wcat, float* __restrict__ bcat,
    const float* __restrict__ Wv, __hip_bfloat16* __restrict__ Wb) {
  const int row = blockIdx.x;  // 0..639
  const int t = threadIdx.x;
  if (row < 384) {
    const float* src = (row < 256) ? (Woff + (size_t)row * ED)
                                   : (Wattn + (size_t)(row - 256) * ED);
    Wcat[(size_t)row * ED + t] = src[t];
    if (t == 0) bcat[row] = (row < 256) ? boff[row] : battn[row - 256];
  } else {
    const int n = row - 384;
    Wb[(size_t)n * ED + t] = __float2bfloat16(Wv[(size_t)n * ED + t]);
  }
}

// ---------------- Post: loc + softmax, in-place in offs[2400 x 384] -----------
__global__ __launch_bounds__(256) void k_post(
    const float* __restrict__ refp, float* __restrict__ offs) {
  __shared__ float lg[128];
  const int t = threadIdx.x;
  const int bq = blockIdx.x;
  float* row = offs + (size_t)bq * 384;
  if (t < 128) lg[t] = row[256 + t];
  const float o = row[t];
  const int c = t & 1;
  const int l = (t >> 3) & 3;
  const float norm = (float)(160 >> l);
  const float r = refp[((size_t)bq * NL + l) * 2 + c];
  __syncthreads();
  row[t] = r + o / norm;
  if (t < NH) {
    float m = -1e30f;
#pragma unroll
    for (int i = 0; i < 16; ++i) m = fmaxf(m, lg[t * 16 + i]);
    float e[16];
    float s = 0.f;
#pragma unroll
    for (int i = 0; i < 16; ++i) {
      e[i] = expf(lg[t * 16 + i] - m);
      s += e[i];
    }
    const float inv = 1.f / s;
#pragma unroll
    for (int i = 0; i < 16; ++i) row[256 + t * 16 + i] = e[i] * inv;
  }
}

// ---------------- Sample: point-parallel bilinear gather + LDS reduce ---------
__device__ __forceinline__ float sample_one(const __hip_bfloat16* __restrict__ vb,
                                            int st, int W, int xi, int yi, int ch) {
  const bool valid = (xi >= 0) & (xi < W) & (yi >= 0) & (yi < W);
  const int xc = min(max(xi, 0), W - 1);
  const int yc = min(max(yi, 0), W - 1);
  const float g = __bfloat162float(vb[((size_t)(st + yc * W + xc)) * ED + ch]);
  return valid ? g : 0.f;
}

__global__ __launch_bounds__(512) void k_sample(
    const __hip_bfloat16* __restrict__ v, const float* __restrict__ offs,
    float* __restrict__ inner) {
  __shared__ float part[16][256];
  __shared__ float slo[256];
  __shared__ float saw[128];
  const int t = threadIdx.x;
  const int bq = blockIdx.x;
  const int b = bq / LQ;
  const float* rowq = offs + (size_t)bq * 384;
  if (t < 256) slo[t] = rowq[t];
  else if (t < 384) saw[t - 256] = rowq[t];
  __syncthreads();

  const int pi = t >> 5;  // 0..15
  const int d = t & 31;
  const int l = pi >> 2;
  const int p = pi & 3;
  const int W = 160 >> l;
  const int st = (l == 0) ? 0 : (l == 1) ? 25600 : (l == 2) ? 32000 : 33600;
  const __hip_bfloat16* vb = v + (size_t)b * LEN_V * ED;

#pragma unroll
  for (int h = 0; h < NH; ++h) {
    const int base = ((h * NL + l) * NP + p) * 2;
    const float lx = slo[base];
    const float ly = slo[base + 1];
    const float w = saw[h * 16 + pi];
    const float x = lx * (float)W - 0.5f;
    const float y = ly * (float)W - 0.5f;
    const float x0f = floorf(x);
    const float y0f = floorf(y);
    const float wx = x - x0f;
    const float wy = y - y0f;
    const int x0 = (int)x0f;
    const int y0 = (int)y0f;
    const int ch = h * 32 + d;
    const float g00 = sample_one(vb, st, W, x0, y0, ch);
    const float g01 = sample_one(vb, st, W, x0 + 1, y0, ch);
    const float g10 = sample_one(vb, st, W, x0, y0 + 1, ch);
    const float g11 = sample_one(vb, st, W, x0 + 1, y0 + 1, ch);
    const float vxy = (g00 * (1.f - wx) + g01 * wx) * (1.f - wy) +
                      (g10 * (1.f - wx) + g11 * wx) * wy;
    part[pi][ch] = w * vxy;
  }
  __syncthreads();
  if (t < 256) {
    float s = 0.f;
#pragma unroll
    for (int q = 0; q < 16; ++q) s += part[q][t];
    inner[(size_t)bq * ED + t] = s;
  }
}

extern "C" void kernel_launch(void* const* d_in, const int* in_sizes, int n_in,
                              void* d_out, int out_size, void* d_ws, size_t ws_size,
                              hipStream_t stream) {
  const float* query = (const float*)d_in[0];
  const float* refp  = (const float*)d_in[1];
  const float* value = (const float*)d_in[2];
  const float* Wv    = (const float*)d_in[3];
  const float* bv    = (const float*)d_in[4];
  const float* Woff  = (const float*)d_in[5];
  const float* boff  = (const float*)d_in[6];
  const float* Wattn = (const float*)d_in[7];
  const float* battn = (const float*)d_in[8];
  const float* Wout  = (const float*)d_in[9];
  const float* bout  = (const float*)d_in[10];
  float* out = (float*)d_out;

  char* ws = (char*)d_ws;
  __hip_bfloat16* v = (__hip_bfloat16*)ws;        // 139,264,000 B
  size_t off = (size_t)BS * LEN_V * ED * 2;
  float* offs = (float*)(ws + off);               // 2400*384*4 = 3.69 MB
  off += (size_t)BS * LQ * 384 * 4;
  float* inner = (float*)(ws + off);              // 2400*256*4 = 2.46 MB
  off += (size_t)BS * LQ * 256 * 4;
  float* Wcat = (float*)(ws + off);               // 384*256*4
  off += (size_t)384 * ED * 4;
  float* bcat = (float*)(ws + off);               // 384*4
  off += 2048;                                     // 384*4 padded
  __hip_bfloat16* Wb = (__hip_bfloat16*)(ws + off); // 256*256*2 = 128KB

  const int M_Q = BS * LQ;  // 2400

  k_concat<<<640, 256, 0, stream>>>(Woff, boff, Wattn, battn, Wcat, bcat, Wv, Wb);
  // value proj: 4250 blocks x 512 thr, B from L2, 1 barrier/block
  k_vproj<<<4250, 512, 0, stream>>>(value, Wb, bv, v);
  // query proj (offsets + attn logits): M=2400 -> 38 blocks, N=384 -> 6
  k_gemm64<float><<<dim3(38, 6), 256, 0, stream>>>(
      query, Wcat, bcat, offs, M_Q, 384);
  k_post<<<M_Q, 256, 0, stream>>>(refp, offs);
  k_sample<<<M_Q, 512, 0, stream>>>(v, offs, inner);
  // out proj: M=2400, N=256 -> (38, 4)
  k_gemm64<float><<<dim3(38, 4), 256, 0, stream>>>(
      inner, Wout, bout, out, M_Q, ED);
}

// Round 5
// 611.579 us; speedup vs baseline: 1.4049x; 1.4049x over previous
//
#include <hip/hip_runtime.h>
#include <hip/hip_bf16.h>

// RT-DETR multi-scale deformable attention, MI355X (gfx950).
// Round 9: R8 structure with the spill fixed. __launch_bounds__(512,4) ->
// 128-VGPR cap (kernel needs ~108). R8's (512,8) capped at 64 and the
// compiler spilled everything (VGPR=32, WRITE 889MB of scratch traffic).
// Structure: B from L2-resident Wb bf16 (no LDS Bs, zero bank conflicts),
// Cs-transpose epilogue with ONE barrier, full-row coalesced short8 stores.

#define BS 8
#define LQ 300
#define LEN_V 34000
#define ED 256
#define NH 8
#define NL 4
#define NP 4

typedef short short8 __attribute__((ext_vector_type(8)));
typedef short sv4 __attribute__((ext_vector_type(4)));
typedef float f32x4 __attribute__((ext_vector_type(4)));

__device__ __forceinline__ short8 cvt8_reg(float4 a, float4 b) {
  union { short8 v; __hip_bfloat16 h[8]; } u;
  u.h[0] = __float2bfloat16(a.x); u.h[1] = __float2bfloat16(a.y);
  u.h[2] = __float2bfloat16(a.z); u.h[3] = __float2bfloat16(a.w);
  u.h[4] = __float2bfloat16(b.x); u.h[5] = __float2bfloat16(b.y);
  u.h[6] = __float2bfloat16(b.z); u.h[7] = __float2bfloat16(b.w);
  return u.v;
}

__device__ __forceinline__ void cvt8_store(__hip_bfloat16* dst, float4 a, float4 b) {
  *(short8*)dst = cvt8_reg(a, b);
}

// ---------------- Value projection: C[272000 x 256] = A @ Wv^T + bv (bf16 out)
// Grid 4250 x 512 thr (8 waves). Block tile 64 rows x 256 cols; wave tile
// 32 rows x 64 cols (acc[2][4]). B-fragments read per-step from global
// Wv_bf16 (128KB, L2-resident). A streams global->reg, 1-deep prefetch,
// cvt in-reg. K-loop barrier-free. Epilogue: acc -> Cs[64][264] (disjoint
// per wave), ONE barrier, then 4 passes of full-row 512B-coherent short8
// stores. ~108 VGPR under the 128 cap -> 2 blocks/CU (50% occ), NO spill.
__global__ __launch_bounds__(512, 4) void k_vproj(
    const float* __restrict__ A, const __hip_bfloat16* __restrict__ Wb,
    const float* __restrict__ bias, __hip_bfloat16* __restrict__ C) {
  __shared__ __align__(16) __hip_bfloat16 Cs[64][264];  // 33,792 B

  const int t = threadIdx.x;
  const int wave = t >> 6;
  const int lane = t & 63;
  const int wr = wave >> 2;        // row-half 0..1 (32 rows each)
  const int wc = wave & 3;         // col-quad 0..3 (64 cols each)
  const int fr = lane & 15;
  const int fk = (lane >> 4) * 8;  // k sub-range within a 32-k step
  const int rq = (lane >> 4) * 4;  // acc row quad

  const size_t row0 = (size_t)blockIdx.x * 64;
  const float* gA = A + (row0 + wr * 32 + fr) * ED + fk;
  const __hip_bfloat16* gB = Wb + (size_t)(wc * 64 + fr) * ED + fk;

  float bias_v[4];
#pragma unroll
  for (int ni = 0; ni < 4; ++ni) bias_v[ni] = bias[wc * 64 + ni * 16 + fr];

  f32x4 acc[2][4];
#pragma unroll
  for (int i = 0; i < 2; ++i)
#pragma unroll
    for (int j = 0; j < 4; ++j) acc[i][j] = (f32x4){0.f, 0.f, 0.f, 0.f};

  float4 c0[2], c1[2];
#pragma unroll
  for (int mi = 0; mi < 2; ++mi) {
    c0[mi] = *(const float4*)(gA + mi * 16 * ED);
    c1[mi] = *(const float4*)(gA + mi * 16 * ED + 4);
  }

#pragma unroll
  for (int s = 0; s < 8; ++s) {
    const int kk = s * 32;
    float4 p0[2], p1[2];
    if (s < 7) {
#pragma unroll
      for (int mi = 0; mi < 2; ++mi) {
        p0[mi] = *(const float4*)(gA + mi * 16 * ED + kk + 32);
        p1[mi] = *(const float4*)(gA + mi * 16 * ED + kk + 36);
      }
    }
    short8 af[2], bf[4];
#pragma unroll
    for (int mi = 0; mi < 2; ++mi) af[mi] = cvt8_reg(c0[mi], c1[mi]);
#pragma unroll
    for (int ni = 0; ni < 4; ++ni)
      bf[ni] = *(const short8*)(gB + (size_t)ni * 16 * ED + kk);
#pragma unroll
    for (int mi = 0; mi < 2; ++mi)
#pragma unroll
      for (int ni = 0; ni < 4; ++ni)
        acc[mi][ni] = __builtin_amdgcn_mfma_f32_16x16x32_bf16(
            af[mi], bf[ni], acc[mi][ni], 0, 0, 0);
    if (s < 7) {
#pragma unroll
      for (int mi = 0; mi < 2; ++mi) { c0[mi] = p0[mi]; c1[mi] = p1[mi]; }
    }
  }

  // ---- epilogue: transpose through Cs (disjoint per wave), one barrier ----
#pragma unroll
  for (int mi = 0; mi < 2; ++mi)
#pragma unroll
    for (int ni = 0; ni < 4; ++ni) {
      const int col = wc * 64 + ni * 16 + fr;
      const int rb = wr * 32 + mi * 16 + rq;
#pragma unroll
      for (int r = 0; r < 4; ++r)
        Cs[rb + r][col] = __float2bfloat16(acc[mi][ni][r] + bias_v[ni]);
    }
  __syncthreads();
  // full-row coherent stores: each pass writes 16 complete 512B rows
#pragma unroll
  for (int p = 0; p < 4; ++p) {
    const int rr = p * 16 + (t >> 5);
    const int cb = (t & 31) * 8;
    *(short8*)(C + (row0 + rr) * ED + cb) = *(const short8*)&Cs[rr][cb];
  }
}

// ---------------- Small MFMA GEMM: C[M x ldc] = A[M x 256] @ B[N x 256]^T + bias
// Block 256 thr (4 waves), tile 64x64, BK=64 (4 K-steps), K=256.
#define LDT64 72  // 64 + 8 pad

template <typename OutT>
__global__ __launch_bounds__(256) void k_gemm64(
    const float* __restrict__ A, const float* __restrict__ B,
    const float* __restrict__ bias, OutT* __restrict__ C, int M, int ldc) {
  __shared__ __align__(16) __hip_bfloat16 As[64][LDT64];
  __shared__ __align__(16) __hip_bfloat16 Bs[64][LDT64];

  const int t = threadIdx.x;
  const size_t row0 = (size_t)blockIdx.x * 64;
  const int n0 = blockIdx.y * 64;

  const int sr = t >> 2;          // staging row 0..63
  const int sc = (t & 3) * 16;    // staging f32 col offset

  const int wave = t >> 6;
  const int lane = t & 63;
  const int mw = (wave & 1) * 32;
  const int nw = (wave >> 1) * 32;
  const int fr = lane & 15;
  const int fk = (lane >> 4) * 8;

  f32x4 acc[2][2];
#pragma unroll
  for (int i = 0; i < 2; ++i)
#pragma unroll
    for (int j = 0; j < 2; ++j) acc[i][j] = (f32x4){0.f, 0.f, 0.f, 0.f};

  const size_t rA = min(row0 + sr, (size_t)(M - 1));
  const float* gA = A + rA * ED + sc;
  const float* gB = B + (size_t)(n0 + sr) * ED + sc;

  for (int kk = 0; kk < ED; kk += 64) {
    float4 a0 = ((const float4*)(gA + kk))[0];
    float4 a1 = ((const float4*)(gA + kk))[1];
    float4 a2 = ((const float4*)(gA + kk))[2];
    float4 a3 = ((const float4*)(gA + kk))[3];
    float4 b0 = ((const float4*)(gB + kk))[0];
    float4 b1 = ((const float4*)(gB + kk))[1];
    float4 b2 = ((const float4*)(gB + kk))[2];
    float4 b3 = ((const float4*)(gB + kk))[3];
    __syncthreads();
    cvt8_store(&As[sr][sc], a0, a1);
    cvt8_store(&As[sr][sc + 8], a2, a3);
    cvt8_store(&Bs[sr][sc], b0, b1);
    cvt8_store(&Bs[sr][sc + 8], b2, b3);
    __syncthreads();

#pragma unroll
    for (int ks = 0; ks < 2; ++ks) {
      short8 afrag[2], bfrag[2];
#pragma unroll
      for (int mi = 0; mi < 2; ++mi)
        afrag[mi] = *(const short8*)&As[mw + mi * 16 + fr][ks * 32 + fk];
#pragma unroll
      for (int ni = 0; ni < 2; ++ni)
        bfrag[ni] = *(const short8*)&Bs[nw + ni * 16 + fr][ks * 32 + fk];
#pragma unroll
      for (int mi = 0; mi < 2; ++mi)
#pragma unroll
        for (int ni = 0; ni < 2; ++ni)
          acc[mi][ni] = __builtin_amdgcn_mfma_f32_16x16x32_bf16(
              afrag[mi], bfrag[ni], acc[mi][ni], 0, 0, 0);
    }
  }

  const int rq = (lane >> 4) * 4;
#pragma unroll
  for (int ni = 0; ni < 2; ++ni) {
    const int col = n0 + nw + ni * 16 + fr;
    const float bias_v = bias[col];
#pragma unroll
    for (int mi = 0; mi < 2; ++mi) {
      const size_t rbase = row0 + mw + mi * 16 + rq;
#pragma unroll
      for (int r = 0; r < 4; ++r) {
        const size_t row = rbase + r;
        if (row < (size_t)M)
          C[row * (size_t)ldc + col] = acc[mi][ni][r] + bias_v;
      }
    }
  }
}

// ---- Concat Woff+Wattn -> Wcat(384x256), and convert Wv -> bf16 (L2-resident B)
__global__ __launch_bounds__(256) void k_concat(
    const float* __restrict__ Woff, const float* __restrict__ boff,
    const float* __restrict__ Wattn, const float* __restrict__ battn,
    float* __restrict__ Wcat, float* __restrict__ bcat,
    const float* __restrict__ Wv, __hip_bfloat16* __restrict__ Wb) {
  const int row = blockIdx.x;  // 0..639
  const int t = threadIdx.x;
  if (row < 384) {
    const float* src = (row < 256) ? (Woff + (size_t)row * ED)
                                   : (Wattn + (size_t)(row - 256) * ED);
    Wcat[(size_t)row * ED + t] = src[t];
    if (t == 0) bcat[row] = (row < 256) ? boff[row] : battn[row - 256];
  } else {
    const int n = row - 384;
    Wb[(size_t)n * ED + t] = __float2bfloat16(Wv[(size_t)n * ED + t]);
  }
}

// ---------------- Post: loc + softmax, in-place in offs[2400 x 384] -----------
__global__ __launch_bounds__(256) void k_post(
    const float* __restrict__ refp, float* __restrict__ offs) {
  __shared__ float lg[128];
  const int t = threadIdx.x;
  const int bq = blockIdx.x;
  float* row = offs + (size_t)bq * 384;
  if (t < 128) lg[t] = row[256 + t];
  const float o = row[t];
  const int c = t & 1;
  const int l = (t >> 3) & 3;
  const float norm = (float)(160 >> l);
  const float r = refp[((size_t)bq * NL + l) * 2 + c];
  __syncthreads();
  row[t] = r + o / norm;
  if (t < NH) {
    float m = -1e30f;
#pragma unroll
    for (int i = 0; i < 16; ++i) m = fmaxf(m, lg[t * 16 + i]);
    float e[16];
    float s = 0.f;
#pragma unroll
    for (int i = 0; i < 16; ++i) {
      e[i] = expf(lg[t * 16 + i] - m);
      s += e[i];
    }
    const float inv = 1.f / s;
#pragma unroll
    for (int i = 0; i < 16; ++i) row[256 + t * 16 + i] = e[i] * inv;
  }
}

// ---------------- Sample: point-parallel bilinear gather + LDS reduce ---------
__device__ __forceinline__ float sample_one(const __hip_bfloat16* __restrict__ vb,
                                            int st, int W, int xi, int yi, int ch) {
  const bool valid = (xi >= 0) & (xi < W) & (yi >= 0) & (yi < W);
  const int xc = min(max(xi, 0), W - 1);
  const int yc = min(max(yi, 0), W - 1);
  const float g = __bfloat162float(vb[((size_t)(st + yc * W + xc)) * ED + ch]);
  return valid ? g : 0.f;
}

__global__ __launch_bounds__(512) void k_sample(
    const __hip_bfloat16* __restrict__ v, const float* __restrict__ offs,
    float* __restrict__ inner) {
  __shared__ float part[16][256];
  __shared__ float slo[256];
  __shared__ float saw[128];
  const int t = threadIdx.x;
  const int bq = blockIdx.x;
  const int b = bq / LQ;
  const float* rowq = offs + (size_t)bq * 384;
  if (t < 256) slo[t] = rowq[t];
  else if (t < 384) saw[t - 256] = rowq[t];
  __syncthreads();

  const int pi = t >> 5;  // 0..15
  const int d = t & 31;
  const int l = pi >> 2;
  const int p = pi & 3;
  const int W = 160 >> l;
  const int st = (l == 0) ? 0 : (l == 1) ? 25600 : (l == 2) ? 32000 : 33600;
  const __hip_bfloat16* vb = v + (size_t)b * LEN_V * ED;

#pragma unroll
  for (int h = 0; h < NH; ++h) {
    const int base = ((h * NL + l) * NP + p) * 2;
    const float lx = slo[base];
    const float ly = slo[base + 1];
    const float w = saw[h * 16 + pi];
    const float x = lx * (float)W - 0.5f;
    const float y = ly * (float)W - 0.5f;
    const float x0f = floorf(x);
    const float y0f = floorf(y);
    const float wx = x - x0f;
    const float wy = y - y0f;
    const int x0 = (int)x0f;
    const int y0 = (int)y0f;
    const int ch = h * 32 + d;
    const float g00 = sample_one(vb, st, W, x0, y0, ch);
    const float g01 = sample_one(vb, st, W, x0 + 1, y0, ch);
    const float g10 = sample_one(vb, st, W, x0, y0 + 1, ch);
    const float g11 = sample_one(vb, st, W, x0 + 1, y0 + 1, ch);
    const float vxy = (g00 * (1.f - wx) + g01 * wx) * (1.f - wy) +
                      (g10 * (1.f - wx) + g11 * wx) * wy;
    part[pi][ch] = w * vxy;
  }
  __syncthreads();
  if (t < 256) {
    float s = 0.f;
#pragma unroll
    for (int q = 0; q < 16; ++q) s += part[q][t];
    inner[(size_t)bq * ED + t] = s;
  }
}

extern "C" void kernel_launch(void* const* d_in, const int* in_sizes, int n_in,
                              void* d_out, int out_size, void* d_ws, size_t ws_size,
                              hipStream_t stream) {
  const float* query = (const float*)d_in[0];
  const float* refp  = (const float*)d_in[1];
  const float* value = (const float*)d_in[2];
  const float* Wv    = (const float*)d_in[3];
  const float* bv    = (const float*)d_in[4];
  const float* Woff  = (const float*)d_in[5];
  const float* boff  = (const float*)d_in[6];
  const float* Wattn = (const float*)d_in[7];
  const float* battn = (const float*)d_in[8];
  const float* Wout  = (const float*)d_in[9];
  const float* bout  = (const float*)d_in[10];
  float* out = (float*)d_out;

  char* ws = (char*)d_ws;
  __hip_bfloat16* v = (__hip_bfloat16*)ws;        // 139,264,000 B
  size_t off = (size_t)BS * LEN_V * ED * 2;
  float* offs = (float*)(ws + off);               // 2400*384*4 = 3.69 MB
  off += (size_t)BS * LQ * 384 * 4;
  float* inner = (float*)(ws + off);              // 2400*256*4 = 2.46 MB
  off += (size_t)BS * LQ * 256 * 4;
  float* Wcat = (float*)(ws + off);               // 384*256*4
  off += (size_t)384 * ED * 4;
  float* bcat = (float*)(ws + off);               // 384*4
  off += 2048;                                     // 384*4 padded
  __hip_bfloat16* Wb = (__hip_bfloat16*)(ws + off); // 256*256*2 = 128KB

  const int M_Q = BS * LQ;  // 2400

  k_concat<<<640, 256, 0, stream>>>(Woff, boff, Wattn, battn, Wcat, bcat, Wv, Wb);
  // value proj: 4250 blocks x 512 thr, B from L2, 1 barrier/block, no spill
  k_vproj<<<4250, 512, 0, stream>>>(value, Wb, bv, v);
  // query proj (offsets + attn logits): M=2400 -> 38 blocks, N=384 -> 6
  k_gemm64<float><<<dim3(38, 6), 256, 0, stream>>>(
      query, Wcat, bcat, offs, M_Q, 384);
  k_post<<<M_Q, 256, 0, stream>>>(refp, offs);
  k_sample<<<M_Q, 512, 0, stream>>>(v, offs, inner);
  // out proj: M=2400, N=256 -> (38, 4)
  k_gemm64<float><<<dim3(38, 4), 256, 0, stream>>>(
      inner, Wout, bout, out, M_Q, ED);
}